// Round 13
// baseline (168.626 us; speedup 1.0000x reference)
//
#include <hip/hip_runtime.h>

#define B_   8
#define N_   8192
#define S_   2048
#define D1_  128
#define D2_  256
#define O_   256
#define BN_  (B_*N_)   // 65536

typedef __bf16 bf16;
typedef __bf16 bf16x8_t __attribute__((ext_vector_type(8)));
typedef __bf16 bf16x4_t __attribute__((ext_vector_type(4)));
typedef float  f32x4_t  __attribute__((ext_vector_type(4)));

// ---------------- workspace layout ----------------
// 0..786432: idx planes (until k_interp); then wimg (k_wprep, 0..327680)
// 393216..1441792: part partials (gemm epilogue, after interp; overlaps dead idx/www tail)
// 786432..1572864: www planes (until k_interp)
static const size_t OFF_IDX  = 0;
static const size_t OFF_W    = 786432;
static const size_t OFF_PRT  = 393216;    // 2 x 256 x 512 f32 = 1 MB
static const size_t OFF_XP   = 1572864;   // x panels [B][48][N][8] bf16 (z2 aliases)
static const size_t OFF_Z    = 51904512;  // f2t (prep->interp), then z1 panels
static const size_t OFF_SS1  = 85458944;
static const size_t OFF_SS2  = 85460992;

#define GL16(gsrc, ldst) \
  __builtin_amdgcn_global_load_lds((const __attribute__((address_space(1))) void*)(gsrc), \
                                   (__attribute__((address_space(3))) void*)(ldst), 16, 0, 0)

// ---------------- kernel 1: MERGED nn3 + prep (interleaved grid, 3072 blocks) ----------------
// nn3 (1024 blocks) is VALU-bound (80% VALUBusy, ~0% HBM); prep (2048 blocks) is HBM-bound.
// Interleave bid%3==0 -> nn3, else prep, so each CU co-hosts both kinds and prep's memory
// traffic hides in nn3's idle issue slots. LDS is a by-branch union (38912 B >= 16640 B).
// Both bodies are byte-identical to round 12's k_nn3 / k_prep.
__global__ __launch_bounds__(256) void k_nn3p(const float* __restrict__ xyz1, const float* __restrict__ xyz2,
                                              int* __restrict__ idxw, float* __restrict__ www,
                                              const float* __restrict__ p1, bf16* __restrict__ xp,
                                              const float* __restrict__ p2, bf16* __restrict__ f2t) {
  __shared__ __align__(16) char raw[38912];
  const int g = blockIdx.x;
  const int t = threadIdx.x;

  if (g % 3 == 0) {
    // ---------------- 3-NN search (exact brute force + noop-eliding wave guard) ----------
    float4 (*sq)[512]    = (float4(*)[512])raw;            // 32768 B
    float  (*pd)[64][3]  = (float(*)[64][3])(raw + 32768); // 3072 B
    int    (*pi)[64][3]  = (int(*)[64][3])(raw + 35840);   // 3072 B
    const int nid  = g / 3;
    const int lane = t & 63, w = t >> 6;      // w = S-chunk 0..3
    const int b     = nid >> 7;
    const int nbase = (nid & 127) * 64;

    const float* x2 = xyz2 + (size_t)b * 3 * S_;
    for (int j = t; j < S_ / 4; j += 256) {
      const float4 x = *(const float4*)(x2 + 4 * j);
      const float4 y = *(const float4*)(x2 + S_ + 4 * j);
      const float4 z = *(const float4*)(x2 + 2 * S_ + 4 * j);
      float4 qq;
      qq.x = fmaf(x.x, x.x, fmaf(y.x, y.x, z.x * z.x));
      qq.y = fmaf(x.y, x.y, fmaf(y.y, y.y, z.y * z.y));
      qq.z = fmaf(x.z, x.z, fmaf(y.z, y.z, z.z * z.z));
      qq.w = fmaf(x.w, x.w, fmaf(y.w, y.w, z.w * z.w));
      sq[0][j] = x; sq[1][j] = y; sq[2][j] = z; sq[3][j] = qq;
    }

    const int n = nbase + lane;
    const float* x1 = xyz1 + (size_t)b * 3 * N_;
    const float px = x1[n], py = x1[N_ + n], pz = x1[2 * N_ + n];
    const float ax = -2.f * px, ay = -2.f * py, az = -2.f * pz;
    __syncthreads();

    float e0 = 3.4e38f, e1 = 3.4e38f, e2 = 3.4e38f;
    int   i0 = 0, i1 = 0, i2 = 0;

    const int jb = w * (S_ / 16);
    #pragma unroll 2
    for (int j = jb; j < jb + S_ / 16; ++j) {
      const float4 qx = sq[0][j], qy = sq[1][j], qz = sq[2][j], qq = sq[3][j];
      #define CAND(C, SI)                                                        \
        {                                                                        \
          const float E = fmaf(ax, qx.C, fmaf(ay, qy.C, fmaf(az, qz.C, qq.C))); \
          if (__any(E < e2)) {                                                   \
            const bool l0 = E < e0, l1 = E < e1, l2 = E < e2;                    \
            const int ni1 = l0 ? i0 : (l1 ? (SI) : i1);                          \
            const int ni2 = l1 ? i1 : (l2 ? (SI) : i2);                          \
            i0 = l0 ? (SI) : i0; i1 = ni1; i2 = ni2;                             \
            const float ne1 = __builtin_amdgcn_fmed3f(E, e0, e1);                \
            const float ne2 = __builtin_amdgcn_fmed3f(E, e1, e2);                \
            e0 = fminf(E, e0); e1 = ne1; e2 = ne2;                               \
          }                                                                      \
        }
      CAND(x, 4 * j + 0)
      CAND(y, 4 * j + 1)
      CAND(z, 4 * j + 2)
      CAND(w, 4 * j + 3)
      #undef CAND
    }

    const float pp = fmaf(px, px, fmaf(py, py, pz * pz));
    pd[w][lane][0] = e0 + pp; pd[w][lane][1] = e1 + pp; pd[w][lane][2] = e2 + pp;
    pi[w][lane][0] = i0; pi[w][lane][1] = i1; pi[w][lane][2] = i2;
    __syncthreads();

    if (t < 64) {
      float d0 = pd[0][t][0], d1 = pd[0][t][1], d2 = pd[0][t][2];
      int   j0 = pi[0][t][0], j1 = pi[0][t][1], j2 = pi[0][t][2];
      #pragma unroll
      for (int ck = 1; ck < 4; ++ck)
        #pragma unroll
        for (int k = 0; k < 3; ++k) {
          const float dv = pd[ck][t][k]; const int iv = pi[ck][t][k];
          const bool c2 = dv < d2, c1 = dv < d1, c0 = dv < d0;
          const float nd2 = c1 ? d1 : (c2 ? dv : d2); const int ni2 = c1 ? j1 : (c2 ? iv : j2);
          const float nd1 = c0 ? d0 : (c1 ? dv : d1); const int ni1 = c0 ? j0 : (c1 ? iv : j1);
          d0 = c0 ? dv : d0; j0 = c0 ? iv : j0;
          d1 = nd1; j1 = ni1; d2 = nd2; j2 = ni2;
        }
      const float r0 = 1.f / (d0 + 1e-8f), r1 = 1.f / (d1 + 1e-8f), r2 = 1.f / (d2 + 1e-8f);
      const float inv = 1.f / (r0 + r1 + r2);
      const int bn = b * N_ + nbase + t;
      idxw[bn] = j0; idxw[BN_ + bn] = j1; idxw[2 * BN_ + bn] = j2;
      www[bn] = r0 * inv; www[BN_ + bn] = r1 * inv; www[2 * BN_ + bn] = r2 * inv;
    }
  } else {
    const int p = g - g / 3 - 1;     // 0..2047 bijective over bid%3!=0
    if (p < 1024) {
      // points1 -> x panels 0..15 (bf16, [B][48][N][8])
      const int gg = p * 256 + t;
      const int n4 = gg & 2047;
      const int c8 = (gg >> 11) & 15;
      const int b  = gg >> 15;
      const int n  = n4 * 4;
      const float* src = p1 + ((size_t)b * D1_ + c8 * 8) * N_ + n;
      bf16x8_t o0, o1, o2, o3;
      #pragma unroll
      for (int j = 0; j < 8; ++j) {
        float4 v = *(const float4*)(src + (size_t)j * N_);
        o0[j] = (bf16)v.x; o1[j] = (bf16)v.y; o2[j] = (bf16)v.z; o3[j] = (bf16)v.w;
      }
      bf16* dst = xp + (((size_t)b * 48 + c8) * N_ + n) * 8;
      *(bf16x8_t*)(dst)      = o0;
      *(bf16x8_t*)(dst + 8)  = o1;
      *(bf16x8_t*)(dst + 16) = o2;
      *(bf16x8_t*)(dst + 24) = o3;
    } else {
      // transpose points2 (B,256,2048) f32 -> f2t (B,2048,256) bf16
      float (*lds)[65] = (float(*)[65])raw;   // 16640 B
      const int bid2 = p - 1024;
      const int b = bid2 & 7;
      const int inner = bid2 >> 3;
      const int s0 = (inner & 31) * 64;
      const int c0 = (inner >> 5) * 64;
      {
        const int cr = t >> 2, scb = (t & 3) * 16;
        const float* src = p2 + ((size_t)b * D2_ + c0 + cr) * S_ + s0 + scb;
        #pragma unroll
        for (int i = 0; i < 4; ++i) {
          const float4 v = *(const float4*)(src + 4 * i);
          lds[cr][scb + 4 * i + 0] = v.x; lds[cr][scb + 4 * i + 1] = v.y;
          lds[cr][scb + 4 * i + 2] = v.z; lds[cr][scb + 4 * i + 3] = v.w;
        }
      }
      __syncthreads();
      const int co = (t & 7) * 8;
      #pragma unroll
      for (int pass = 0; pass < 2; ++pass) {
        const int s = pass * 32 + (t >> 3);
        bf16x8_t o;
        #pragma unroll
        for (int j = 0; j < 8; ++j) o[j] = (bf16)lds[co + j][s];
        *(bf16x8_t*)(f2t + ((size_t)b * S_ + s0 + s) * D2_ + c0 + co) = o;
      }
    }
  }
}

// ---------------- kernel 2: gather-interp -> x panels 16..47 ----------------
__global__ __launch_bounds__(256) void k_interp(const bf16* __restrict__ f2t, const int* __restrict__ idxw,
                                                const float* __restrict__ www, bf16* __restrict__ xp) {
  const int bid = blockIdx.x;
  const int b = bid & 7;
  const int n = (bid >> 3) * 8 + (threadIdx.x & 7);
  const int c8 = threadIdx.x >> 3;
  const int bn = b * N_ + n;
  const int j0 = idxw[bn], j1 = idxw[BN_ + bn], j2 = idxw[2 * BN_ + bn];
  const float w0 = www[bn], w1 = www[BN_ + bn], w2 = www[2 * BN_ + bn];
  const bf16* base = f2t + (size_t)b * S_ * D2_ + c8 * 8;
  const bf16x8_t v0 = *(const bf16x8_t*)(base + (size_t)j0 * D2_);
  const bf16x8_t v1 = *(const bf16x8_t*)(base + (size_t)j1 * D2_);
  const bf16x8_t v2 = *(const bf16x8_t*)(base + (size_t)j2 * D2_);
  bf16x8_t out;
  #pragma unroll
  for (int j = 0; j < 8; ++j)
    out[j] = (bf16)(w0 * (float)v0[j] + w1 * (float)v1[j] + w2 * (float)v2[j]);
  *(bf16x8_t*)(xp + (((size_t)b * 48 + 16 + c8) * N_ + (size_t)n) * 8) = out;
}

// ---------------- kernel 3: W fp32 -> bf16 LDS-image panels ----------------
__global__ __launch_bounds__(256) void k_wprep(const float* __restrict__ W1, const float* __restrict__ W2,
                                               bf16* __restrict__ img) {
  const int g = blockIdx.x * 256 + threadIdx.x;   // 80 blocks
  if (g < 12288) {
    const int e = g * 8;
    const int imgblk = e >> 12, r = e & 4095;
    const int kc = r >> 10, row = (r & 1023) >> 3;
    const int mblk = imgblk / 12, kt32 = imgblk % 12;
    const float* s = W1 + (size_t)(mblk * 128 + row) * 384 + kt32 * 32 + kc * 8;
    const float4 f0 = *(const float4*)(s), f1 = *(const float4*)(s + 4);
    bf16x8_t h;
    h[0] = (bf16)f0.x; h[1] = (bf16)f0.y; h[2] = (bf16)f0.z; h[3] = (bf16)f0.w;
    h[4] = (bf16)f1.x; h[5] = (bf16)f1.y; h[6] = (bf16)f1.z; h[7] = (bf16)f1.w;
    *(bf16x8_t*)(img + e) = h;
  } else if (g < 20480) {
    const int e = (g - 12288) * 8;
    const int imgblk = e >> 12, r = e & 4095;
    const int kc = r >> 10, row = (r & 1023) >> 3;
    const int mblk = imgblk >> 3, kt32 = imgblk & 7;
    const float* s = W2 + (size_t)(mblk * 128 + row) * 256 + kt32 * 32 + kc * 8;
    const float4 f0 = *(const float4*)(s), f1 = *(const float4*)(s + 4);
    bf16x8_t h;
    h[0] = (bf16)f0.x; h[1] = (bf16)f0.y; h[2] = (bf16)f0.z; h[3] = (bf16)f0.w;
    h[4] = (bf16)f1.x; h[5] = (bf16)f1.y; h[6] = (bf16)f1.z; h[7] = (bf16)f1.w;
    *(bf16x8_t*)(img + 98304 + e) = h;
  }
}

// ---------------- kernel 4: GEMM1 via global_load_lds, XCD-swizzled, FUSED BN-STATS ---------
template<int K>
__global__ __launch_bounds__(256) void k_gemm(const bf16* __restrict__ Wimg, const float* __restrict__ bias,
                                              const bf16* __restrict__ X, bf16* __restrict__ Zp,
                                              float* __restrict__ part) {
  __shared__ bf16 As[4096];   // [kc(4)][row m(128)][kk(8)]
  __shared__ bf16 Bt[4096];
  __shared__ float stl[2][128][2];
  const int tid = threadIdx.x;
  const int lane = tid & 63, wid = tid >> 6;
  const int wr = wid >> 1, wc = wid & 1;
  const int dd = blockIdx.x;
  const int xcd = dd & 7, pos = dd >> 3;
  const int b = pos >> 4, q = pos & 15;
  const int m0 = (q & 1) * 128;
  const int ncol = xcd * 8 + (q >> 1);
  const int n0 = ncol * 128;
  const int mblk = m0 >> 7;
  const int l15 = lane & 15, l4 = lane >> 4;

  f32x4_t acc[4][4];
  #pragma unroll
  for (int i = 0; i < 4; ++i)
    #pragma unroll
    for (int j = 0; j < 4; ++j) { f32x4_t z = {0.f, 0.f, 0.f, 0.f}; acc[i][j] = z; }

  const bf16* Xb = X + (size_t)b * (K / 8) * ((size_t)N_ * 8);

  for (int kt = 0; kt < K; kt += 32) {
    const bf16* asrc = Wimg + (size_t)(mblk * (K / 32) + (kt >> 5)) * 4096 + wid * 1024 + lane * 8;
    GL16(asrc,       &As[wid * 1024]);
    GL16(asrc + 512, &As[wid * 1024 + 512]);
    const bf16* bsrc = Xb + ((size_t)(kt >> 3) + wid) * ((size_t)N_ * 8) + ((size_t)n0 + lane) * 8;
    GL16(bsrc,       &Bt[wid * 1024]);
    GL16(bsrc + 512, &Bt[wid * 1024 + 512]);
    __syncthreads();
    bf16x8_t af[4], bfr[4];
    #pragma unroll
    for (int mi = 0; mi < 4; ++mi) af[mi]  = *(const bf16x8_t*)&As[l4 * 1024 + (wr * 64 + mi * 16 + l15) * 8];
    #pragma unroll
    for (int ni = 0; ni < 4; ++ni) bfr[ni] = *(const bf16x8_t*)&Bt[l4 * 1024 + (wc * 64 + ni * 16 + l15) * 8];
    #pragma unroll
    for (int mi = 0; mi < 4; ++mi)
      #pragma unroll
      for (int ni = 0; ni < 4; ++ni)
        acc[mi][ni] = __builtin_amdgcn_mfma_f32_16x16x32_bf16(af[mi], bfr[ni], acc[mi][ni], 0, 0, 0);
    __syncthreads();
  }
  bf16* Zb = Zp + (size_t)b * 32 * ((size_t)N_ * 8);
  #pragma unroll
  for (int mi = 0; mi < 4; ++mi) {
    const int obase = m0 + wr * 64 + mi * 16 + l4 * 4;
    const float4 bv = *(const float4*)(bias + obase);
    const size_t gofs = (size_t)(obase >> 3) * ((size_t)N_ * 8) + (obase & 7);
    float sv0 = 0.f, sv1 = 0.f, sv2 = 0.f, sv3 = 0.f;
    float qv0 = 0.f, qv1 = 0.f, qv2 = 0.f, qv3 = 0.f;
    #pragma unroll
    for (int ni = 0; ni < 4; ++ni) {
      const int nn = n0 + wc * 64 + ni * 16 + l15;
      const float v0 = acc[mi][ni][0] + bv.x;
      const float v1 = acc[mi][ni][1] + bv.y;
      const float v2 = acc[mi][ni][2] + bv.z;
      const float v3 = acc[mi][ni][3] + bv.w;
      bf16x4_t o;
      o[0] = (bf16)v0; o[1] = (bf16)v1; o[2] = (bf16)v2; o[3] = (bf16)v3;
      *(bf16x4_t*)(Zb + gofs + (size_t)nn * 8) = o;
      sv0 += v0; qv0 = fmaf(v0, v0, qv0);
      sv1 += v1; qv1 = fmaf(v1, v1, qv1);
      sv2 += v2; qv2 = fmaf(v2, v2, qv2);
      sv3 += v3; qv3 = fmaf(v3, v3, qv3);
    }
    #pragma unroll
    for (int off = 1; off < 16; off <<= 1) {
      sv0 += __shfl_xor(sv0, off); qv0 += __shfl_xor(qv0, off);
      sv1 += __shfl_xor(sv1, off); qv1 += __shfl_xor(qv1, off);
      sv2 += __shfl_xor(sv2, off); qv2 += __shfl_xor(qv2, off);
      sv3 += __shfl_xor(sv3, off); qv3 += __shfl_xor(qv3, off);
    }
    if (l15 == 0) {
      const int ol = wr * 64 + mi * 16 + l4 * 4;
      stl[wc][ol + 0][0] = sv0; stl[wc][ol + 0][1] = qv0;
      stl[wc][ol + 1][0] = sv1; stl[wc][ol + 1][1] = qv1;
      stl[wc][ol + 2][0] = sv2; stl[wc][ol + 2][1] = qv2;
      stl[wc][ol + 3][0] = sv3; stl[wc][ol + 3][1] = qv3;
    }
  }
  __syncthreads();
  if (tid < 128) {
    const float s  = stl[0][tid][0] + stl[1][tid][0];
    const float sq = stl[0][tid][1] + stl[1][tid][1];
    const int ib = b * 64 + ncol;
    part[(size_t)(m0 + tid) * 512 + ib]       = s;
    part[(size_t)(256 + m0 + tid) * 512 + ib] = sq;
  }
}

// ---------------- kernel 4b: GEMM2 with FUSED BN1+ReLU on B-staging ----------
__global__ __launch_bounds__(256) void k_gemm2f(const bf16* __restrict__ Wimg, const float* __restrict__ bias,
                                                const bf16* __restrict__ Z1, const float* __restrict__ ss,
                                                bf16* __restrict__ Zp, float* __restrict__ part) {
  __shared__ bf16 As[4096];
  __shared__ bf16 Bt[4096];
  __shared__ float stl[2][128][2];
  __shared__ float ssl[512];
  const int tid = threadIdx.x;
  const int lane = tid & 63, wid = tid >> 6;
  const int wr = wid >> 1, wc = wid & 1;
  const int dd = blockIdx.x;
  const int xcd = dd & 7, pos = dd >> 3;
  const int b = pos >> 4, q = pos & 15;
  const int m0 = (q & 1) * 128;
  const int ncol = xcd * 8 + (q >> 1);
  const int n0 = ncol * 128;
  const int mblk = m0 >> 7;
  const int l15 = lane & 15, l4 = lane >> 4;

  ssl[tid] = ss[tid]; ssl[256 + tid] = ss[256 + tid];

  f32x4_t acc[4][4];
  #pragma unroll
  for (int i = 0; i < 4; ++i)
    #pragma unroll
    for (int j = 0; j < 4; ++j) { f32x4_t z = {0.f, 0.f, 0.f, 0.f}; acc[i][j] = z; }

  const bf16* Z1b = Z1 + (size_t)b * 32 * ((size_t)N_ * 8);
  __syncthreads();   // ssl ready

  for (int kt = 0; kt < 256; kt += 32) {
    const bf16* asrc = Wimg + (size_t)(mblk * 8 + (kt >> 5)) * 4096 + wid * 1024 + lane * 8;
    GL16(asrc,       &As[wid * 1024]);
    GL16(asrc + 512, &As[wid * 1024 + 512]);
    const int kc8 = (kt >> 3) + wid;
    const bf16* bsrc = Z1b + (size_t)kc8 * ((size_t)N_ * 8) + ((size_t)n0 + lane) * 8;
    const bf16x8_t rb0 = *(const bf16x8_t*)(bsrc);
    const bf16x8_t rb1 = *(const bf16x8_t*)(bsrc + 512);
    const int cb = kc8 * 8;
    bf16x8_t ob0, ob1;
    #pragma unroll
    for (int j = 0; j < 8; ++j) {
      const float sc = ssl[cb + j], sh = ssl[256 + cb + j];
      ob0[j] = (bf16)fmaxf(fmaf((float)rb0[j], sc, sh), 0.f);
      ob1[j] = (bf16)fmaxf(fmaf((float)rb1[j], sc, sh), 0.f);
    }
    *(bf16x8_t*)&Bt[wid * 1024 + lane * 8]       = ob0;
    *(bf16x8_t*)&Bt[wid * 1024 + 512 + lane * 8] = ob1;
    __syncthreads();
    bf16x8_t af[4], bfr[4];
    #pragma unroll
    for (int mi = 0; mi < 4; ++mi) af[mi]  = *(const bf16x8_t*)&As[l4 * 1024 + (wr * 64 + mi * 16 + l15) * 8];
    #pragma unroll
    for (int ni = 0; ni < 4; ++ni) bfr[ni] = *(const bf16x8_t*)&Bt[l4 * 1024 + (wc * 64 + ni * 16 + l15) * 8];
    #pragma unroll
    for (int mi = 0; mi < 4; ++mi)
      #pragma unroll
      for (int ni = 0; ni < 4; ++ni)
        acc[mi][ni] = __builtin_amdgcn_mfma_f32_16x16x32_bf16(af[mi], bfr[ni], acc[mi][ni], 0, 0, 0);
    __syncthreads();
  }
  bf16* Zb = Zp + (size_t)b * 32 * ((size_t)N_ * 8);
  #pragma unroll
  for (int mi = 0; mi < 4; ++mi) {
    const int obase = m0 + wr * 64 + mi * 16 + l4 * 4;
    const float4 bv = *(const float4*)(bias + obase);
    const size_t gofs = (size_t)(obase >> 3) * ((size_t)N_ * 8) + (obase & 7);
    float sv0 = 0.f, sv1 = 0.f, sv2 = 0.f, sv3 = 0.f;
    float qv0 = 0.f, qv1 = 0.f, qv2 = 0.f, qv3 = 0.f;
    #pragma unroll
    for (int ni = 0; ni < 4; ++ni) {
      const int nn = n0 + wc * 64 + ni * 16 + l15;
      const float v0 = acc[mi][ni][0] + bv.x;
      const float v1 = acc[mi][ni][1] + bv.y;
      const float v2 = acc[mi][ni][2] + bv.z;
      const float v3 = acc[mi][ni][3] + bv.w;
      bf16x4_t o;
      o[0] = (bf16)v0; o[1] = (bf16)v1; o[2] = (bf16)v2; o[3] = (bf16)v3;
      *(bf16x4_t*)(Zb + gofs + (size_t)nn * 8) = o;
      sv0 += v0; qv0 = fmaf(v0, v0, qv0);
      sv1 += v1; qv1 = fmaf(v1, v1, qv1);
      sv2 += v2; qv2 = fmaf(v2, v2, qv2);
      sv3 += v3; qv3 = fmaf(v3, v3, qv3);
    }
    #pragma unroll
    for (int off = 1; off < 16; off <<= 1) {
      sv0 += __shfl_xor(sv0, off); qv0 += __shfl_xor(qv0, off);
      sv1 += __shfl_xor(sv1, off); qv1 += __shfl_xor(qv1, off);
      sv2 += __shfl_xor(sv2, off); qv2 += __shfl_xor(qv2, off);
      sv3 += __shfl_xor(sv3, off); qv3 += __shfl_xor(qv3, off);
    }
    if (l15 == 0) {
      const int ol = wr * 64 + mi * 16 + l4 * 4;
      stl[wc][ol + 0][0] = sv0; stl[wc][ol + 0][1] = qv0;
      stl[wc][ol + 1][0] = sv1; stl[wc][ol + 1][1] = qv1;
      stl[wc][ol + 2][0] = sv2; stl[wc][ol + 2][1] = qv2;
      stl[wc][ol + 3][0] = sv3; stl[wc][ol + 3][1] = qv3;
    }
  }
  __syncthreads();
  if (tid < 128) {
    const float s  = stl[0][tid][0] + stl[1][tid][0];
    const float sq = stl[0][tid][1] + stl[1][tid][1];
    const int ib = b * 64 + ncol;
    part[(size_t)(m0 + tid) * 512 + ib]       = s;
    part[(size_t)(256 + m0 + tid) * 512 + ib] = sq;
  }
}

// ---------------- kernel 5: finalize scale/shift from partials (256 blocks) ----------------
__global__ __launch_bounds__(256) void k_ss(const float* __restrict__ part, const float* __restrict__ g,
                                            const float* __restrict__ be, float* __restrict__ ss) {
  const int c = blockIdx.x, t = threadIdx.x;
  float s  = part[(size_t)c * 512 + t]         + part[(size_t)c * 512 + t + 256];
  float qv = part[(size_t)(256 + c) * 512 + t] + part[(size_t)(256 + c) * 512 + t + 256];
  #pragma unroll
  for (int off = 32; off; off >>= 1) { s += __shfl_down(s, off); qv += __shfl_down(qv, off); }
  __shared__ float r[8];
  const int w = t >> 6;
  if ((t & 63) == 0) { r[w] = s; r[4 + w] = qv; }
  __syncthreads();
  if (t == 0) {
    s  = r[0] + r[1] + r[2] + r[3];
    qv = r[4] + r[5] + r[6] + r[7];
    const float mean = s * (1.f / 65536.f);
    const float var  = qv * (1.f / 65536.f) - mean * mean;
    const float rstd = rsqrtf(var + 1e-5f);
    const float sc = g[c] * rstd;
    ss[c] = sc; ss[O_ + c] = be[c] - mean * sc;
  }
}

// ---------------- kernel 6: final BN+ReLU, panels -> Y fp32 [B][256][N] ----------------
__global__ __launch_bounds__(256) void k_final_p(const bf16* __restrict__ Z, const float* __restrict__ ss,
                                                 float* __restrict__ Y) {
  const int b  = blockIdx.x >> 7;
  const int n0 = (blockIdx.x & 127) * 64;
  const int og = threadIdx.x >> 3, ns = threadIdx.x & 7;
  const bf16* src = Z + (((size_t)b * 32 + og) * N_ + n0 + ns * 8) * 8;
  bf16x8_t v[8];
  #pragma unroll
  for (int i = 0; i < 8; ++i) v[i] = *(const bf16x8_t*)(src + i * 8);
  float sc[8], sh[8];
  #pragma unroll
  for (int j = 0; j < 8; ++j) { sc[j] = ss[og * 8 + j]; sh[j] = ss[O_ + og * 8 + j]; }
  float* dst = Y + ((size_t)b * O_ + og * 8) * N_ + n0 + ns * 8;
  #pragma unroll
  for (int j = 0; j < 8; ++j) {
    float4 a0, a1;
    a0.x = fmaxf(fmaf((float)v[0][j], sc[j], sh[j]), 0.f);
    a0.y = fmaxf(fmaf((float)v[1][j], sc[j], sh[j]), 0.f);
    a0.z = fmaxf(fmaf((float)v[2][j], sc[j], sh[j]), 0.f);
    a0.w = fmaxf(fmaf((float)v[3][j], sc[j], sh[j]), 0.f);
    a1.x = fmaxf(fmaf((float)v[4][j], sc[j], sh[j]), 0.f);
    a1.y = fmaxf(fmaf((float)v[5][j], sc[j], sh[j]), 0.f);
    a1.z = fmaxf(fmaf((float)v[6][j], sc[j], sh[j]), 0.f);
    a1.w = fmaxf(fmaf((float)v[7][j], sc[j], sh[j]), 0.f);
    *(float4*)(dst + (size_t)j * N_)     = a0;
    *(float4*)(dst + (size_t)j * N_ + 4) = a1;
  }
}

extern "C" void kernel_launch(void* const* d_in, const int* in_sizes, int n_in,
                              void* d_out, int out_size, void* d_ws, size_t ws_size,
                              hipStream_t stream) {
  const float* xyz1    = (const float*)d_in[0];
  const float* xyz2    = (const float*)d_in[1];
  const float* points1 = (const float*)d_in[2];
  const float* points2 = (const float*)d_in[3];
  const float* W1  = (const float*)d_in[4];
  const float* b1  = (const float*)d_in[5];
  const float* g1  = (const float*)d_in[6];
  const float* be1 = (const float*)d_in[7];
  const float* W2  = (const float*)d_in[8];
  const float* b2  = (const float*)d_in[9];
  const float* g2  = (const float*)d_in[10];
  const float* be2 = (const float*)d_in[11];
  float* Y = (float*)d_out;
  char*  ws = (char*)d_ws;
  int*   idxw  = (int*)(ws + OFF_IDX);
  float* www   = (float*)(ws + OFF_W);
  bf16*  wimg1 = (bf16*)(ws + OFF_IDX);   // reuses idx region AFTER k_interp
  bf16*  wimg2 = wimg1 + 98304;
  float* part  = (float*)(ws + OFF_PRT);  // reuses idx/www tail AFTER k_interp
  bf16*  xp    = (bf16*)(ws + OFF_XP);
  bf16*  z1    = (bf16*)(ws + OFF_Z);     // also f2t (disjoint lifetime)
  bf16*  f2t   = (bf16*)(ws + OFF_Z);
  bf16*  z2    = (bf16*)(ws + OFF_XP);    // aliases xp (dead after gemm1)
  float* ss1   = (float*)(ws + OFF_SS1);
  float* ss2   = (float*)(ws + OFF_SS2);

  hipLaunchKernelGGL(k_nn3p, dim3(3072), dim3(256), 0, stream,
                     xyz1, xyz2, idxw, www, points1, xp, points2, f2t);
  hipLaunchKernelGGL(k_interp, dim3(8192), dim3(256), 0, stream, f2t, idxw, www, xp);
  hipLaunchKernelGGL(k_wprep, dim3(80), dim3(256), 0, stream, W1, W2, wimg1);
  hipLaunchKernelGGL((k_gemm<384>), dim3(1024), dim3(256), 0, stream, wimg1, b1, xp, z1, part);
  hipLaunchKernelGGL(k_ss, dim3(256), dim3(256), 0, stream, part, g1, be1, ss1);
  hipLaunchKernelGGL(k_gemm2f, dim3(1024), dim3(256), 0, stream, wimg2, b2, z1, ss1, z2, part);
  hipLaunchKernelGGL(k_ss, dim3(256), dim3(256), 0, stream, part, g2, be2, ss2);
  hipLaunchKernelGGL(k_final_p, dim3(1024), dim3(256), 0, stream, z2, ss2, Y);
}

// Round 14
// 163.972 us; speedup vs baseline: 1.0284x; 1.0284x over previous
//
#include <hip/hip_runtime.h>

#define B_   8
#define N_   8192
#define S_   2048
#define D1_  128
#define D2_  256
#define O_   256
#define BN_  (B_*N_)   // 65536

typedef __bf16 bf16;
typedef __bf16 bf16x8_t __attribute__((ext_vector_type(8)));
typedef __bf16 bf16x4_t __attribute__((ext_vector_type(4)));
typedef float  f32x4_t  __attribute__((ext_vector_type(4)));

// ---------------- workspace layout ----------------
// 0..786432: idx planes (until k_interp); then wimg (k_wprep, 0..327680)
// 393216..1441792: part partials (gemm epilogue, after interp; overlaps dead idx/www tail)
// 786432..1572864: www planes (until k_interp)
static const size_t OFF_IDX  = 0;
static const size_t OFF_W    = 786432;
static const size_t OFF_PRT  = 393216;    // 2 x 256 x 512 f32 = 1 MB
static const size_t OFF_XP   = 1572864;   // x panels [B][48][N][8] bf16 (z2 aliases)
static const size_t OFF_Z    = 51904512;  // f2t (prep->interp), then z1 panels
static const size_t OFF_SS1  = 85458944;
static const size_t OFF_SS2  = 85460992;

#define GL16(gsrc, ldst) \
  __builtin_amdgcn_global_load_lds((const __attribute__((address_space(1))) void*)(gsrc), \
                                   (__attribute__((address_space(3))) void*)(ldst), 16, 0, 0)

// ---------------- kernel 1: merged prep — conv_p1 (blocks 0..1023) + t2 (1024..2047) --------
// NOTE (r13 lesson): do NOT merge this into k_nn3 — nn3 is VALU-issue-bound (80% busy);
// co-scheduled prep waves steal issue slots 1:1 (measured 56 -> 75.9 us, = 56/0.75).
__global__ __launch_bounds__(256) void k_prep(const float* __restrict__ p1, bf16* __restrict__ xp,
                                              const float* __restrict__ p2, bf16* __restrict__ f2t) {
  __shared__ float lds[64][65];   // used by t2 branch only
  const int bid = blockIdx.x;
  const int t = threadIdx.x;
  if (bid < 1024) {
    const int g  = bid * 256 + t;
    const int n4 = g & 2047;
    const int c8 = (g >> 11) & 15;
    const int b  = g >> 15;
    const int n  = n4 * 4;
    const float* src = p1 + ((size_t)b * D1_ + c8 * 8) * N_ + n;
    bf16x8_t o0, o1, o2, o3;
    #pragma unroll
    for (int j = 0; j < 8; ++j) {
      float4 v = *(const float4*)(src + (size_t)j * N_);
      o0[j] = (bf16)v.x; o1[j] = (bf16)v.y; o2[j] = (bf16)v.z; o3[j] = (bf16)v.w;
    }
    bf16* dst = xp + (((size_t)b * 48 + c8) * N_ + n) * 8;
    *(bf16x8_t*)(dst)      = o0;
    *(bf16x8_t*)(dst + 8)  = o1;
    *(bf16x8_t*)(dst + 16) = o2;
    *(bf16x8_t*)(dst + 24) = o3;
  } else {
    const int bid2 = bid - 1024;
    const int b = bid2 & 7;
    const int inner = bid2 >> 3;
    const int s0 = (inner & 31) * 64;
    const int c0 = (inner >> 5) * 64;
    {
      const int cr = t >> 2, scb = (t & 3) * 16;
      const float* src = p2 + ((size_t)b * D2_ + c0 + cr) * S_ + s0 + scb;
      #pragma unroll
      for (int i = 0; i < 4; ++i) {
        const float4 v = *(const float4*)(src + 4 * i);
        lds[cr][scb + 4 * i + 0] = v.x; lds[cr][scb + 4 * i + 1] = v.y;
        lds[cr][scb + 4 * i + 2] = v.z; lds[cr][scb + 4 * i + 3] = v.w;
      }
    }
    __syncthreads();
    const int co = (t & 7) * 8;
    #pragma unroll
    for (int pass = 0; pass < 2; ++pass) {
      const int s = pass * 32 + (t >> 3);
      bf16x8_t o;
      #pragma unroll
      for (int j = 0; j < 8; ++j) o[j] = (bf16)lds[co + j][s];
      *(bf16x8_t*)(f2t + ((size_t)b * S_ + s0 + s) * D2_ + c0 + co) = o;
    }
  }
}

// ---------------- kernel 2: 3-NN search (exact brute force + noop-eliding wave guard) -------
__device__ __forceinline__ void ins3(float d, int i,
                                     float& d0, float& d1, float& d2,
                                     int& i0, int& i1, int& i2) {
  const bool c2 = d < d2, c1 = d < d1, c0 = d < d0;
  const float nd2 = c1 ? d1 : (c2 ? d : d2); const int ni2 = c1 ? i1 : (c2 ? i : i2);
  const float nd1 = c0 ? d0 : (c1 ? d : d1); const int ni1 = c0 ? i0 : (c1 ? i : i1);
  d0 = c0 ? d : d0; i0 = c0 ? i : i0;
  d1 = nd1; i1 = ni1; d2 = nd2; i2 = ni2;
}

__global__ __launch_bounds__(256) void k_nn3(const float* __restrict__ xyz1, const float* __restrict__ xyz2,
                                             int* __restrict__ idxw, float* __restrict__ www) {
  __shared__ float4 sq[4][S_ / 4];   // x,y,z,|q|^2 planes (32 KB)
  __shared__ float  pd[4][64][3];
  __shared__ int    pi[4][64][3];
  const int tid  = threadIdx.x;
  const int lane = tid & 63, w = tid >> 6;     // w = S-chunk 0..3
  const int b     = blockIdx.y;
  const int nbase = blockIdx.x * 64;

  const float* x2 = xyz2 + (size_t)b * 3 * S_;
  for (int j = tid; j < S_ / 4; j += 256) {
    const float4 x = *(const float4*)(x2 + 4 * j);
    const float4 y = *(const float4*)(x2 + S_ + 4 * j);
    const float4 z = *(const float4*)(x2 + 2 * S_ + 4 * j);
    float4 qq;
    qq.x = fmaf(x.x, x.x, fmaf(y.x, y.x, z.x * z.x));
    qq.y = fmaf(x.y, x.y, fmaf(y.y, y.y, z.y * z.y));
    qq.z = fmaf(x.z, x.z, fmaf(y.z, y.z, z.z * z.z));
    qq.w = fmaf(x.w, x.w, fmaf(y.w, y.w, z.w * z.w));
    sq[0][j] = x; sq[1][j] = y; sq[2][j] = z; sq[3][j] = qq;
  }

  const int n = nbase + lane;
  const float* x1 = xyz1 + (size_t)b * 3 * N_;
  const float px = x1[n], py = x1[N_ + n], pz = x1[2 * N_ + n];
  const float ax = -2.f * px, ay = -2.f * py, az = -2.f * pz;
  __syncthreads();

  float e0 = 3.4e38f, e1 = 3.4e38f, e2 = 3.4e38f;
  int   i0 = 0, i1 = 0, i2 = 0;

  const int jb = w * (S_ / 16);    // 128 float4 groups per chunk
  #pragma unroll 2
  for (int j = jb; j < jb + S_ / 16; ++j) {
    const float4 qx = sq[0][j], qy = sq[1][j], qz = sq[2][j], qq = sq[3][j];
    #define CAND(C, SI)                                                        \
      {                                                                        \
        const float E = fmaf(ax, qx.C, fmaf(ay, qy.C, fmaf(az, qz.C, qq.C))); \
        if (__any(E < e2)) {                                                   \
          const bool l0 = E < e0, l1 = E < e1, l2 = E < e2;                    \
          const int ni1 = l0 ? i0 : (l1 ? (SI) : i1);                          \
          const int ni2 = l1 ? i1 : (l2 ? (SI) : i2);                          \
          i0 = l0 ? (SI) : i0; i1 = ni1; i2 = ni2;                             \
          const float ne1 = __builtin_amdgcn_fmed3f(E, e0, e1);                \
          const float ne2 = __builtin_amdgcn_fmed3f(E, e1, e2);                \
          e0 = fminf(E, e0); e1 = ne1; e2 = ne2;                               \
        }                                                                      \
      }
    CAND(x, 4 * j + 0)
    CAND(y, 4 * j + 1)
    CAND(z, 4 * j + 2)
    CAND(w, 4 * j + 3)
    #undef CAND
  }

  const float pp = fmaf(px, px, fmaf(py, py, pz * pz));
  pd[w][lane][0] = e0 + pp; pd[w][lane][1] = e1 + pp; pd[w][lane][2] = e2 + pp;
  pi[w][lane][0] = i0; pi[w][lane][1] = i1; pi[w][lane][2] = i2;
  __syncthreads();

  if (tid < 64) {
    float d0 = pd[0][tid][0], d1 = pd[0][tid][1], d2 = pd[0][tid][2];
    int   j0 = pi[0][tid][0], j1 = pi[0][tid][1], j2 = pi[0][tid][2];
    #pragma unroll
    for (int ck = 1; ck < 4; ++ck)
      #pragma unroll
      for (int k = 0; k < 3; ++k)
        ins3(pd[ck][tid][k], pi[ck][tid][k], d0, d1, d2, j0, j1, j2);
    const float r0 = 1.f / (d0 + 1e-8f), r1 = 1.f / (d1 + 1e-8f), r2 = 1.f / (d2 + 1e-8f);
    const float inv = 1.f / (r0 + r1 + r2);
    const int bn = b * N_ + nbase + tid;
    idxw[bn] = j0; idxw[BN_ + bn] = j1; idxw[2 * BN_ + bn] = j2;
    www[bn] = r0 * inv; www[BN_ + bn] = r1 * inv; www[2 * BN_ + bn] = r2 * inv;
  }
}

// ---------------- kernel 3: gather-interp -> x panels 16..47 ----------------
__global__ __launch_bounds__(256) void k_interp(const bf16* __restrict__ f2t, const int* __restrict__ idxw,
                                                const float* __restrict__ www, bf16* __restrict__ xp) {
  const int bid = blockIdx.x;
  const int b = bid & 7;
  const int n = (bid >> 3) * 8 + (threadIdx.x & 7);
  const int c8 = threadIdx.x >> 3;
  const int bn = b * N_ + n;
  const int j0 = idxw[bn], j1 = idxw[BN_ + bn], j2 = idxw[2 * BN_ + bn];
  const float w0 = www[bn], w1 = www[BN_ + bn], w2 = www[2 * BN_ + bn];
  const bf16* base = f2t + (size_t)b * S_ * D2_ + c8 * 8;
  const bf16x8_t v0 = *(const bf16x8_t*)(base + (size_t)j0 * D2_);
  const bf16x8_t v1 = *(const bf16x8_t*)(base + (size_t)j1 * D2_);
  const bf16x8_t v2 = *(const bf16x8_t*)(base + (size_t)j2 * D2_);
  bf16x8_t out;
  #pragma unroll
  for (int j = 0; j < 8; ++j)
    out[j] = (bf16)(w0 * (float)v0[j] + w1 * (float)v1[j] + w2 * (float)v2[j]);
  *(bf16x8_t*)(xp + (((size_t)b * 48 + 16 + c8) * N_ + (size_t)n) * 8) = out;
}

// ---------------- kernel 4: W fp32 -> bf16 LDS-image panels ----------------
__global__ __launch_bounds__(256) void k_wprep(const float* __restrict__ W1, const float* __restrict__ W2,
                                               bf16* __restrict__ img) {
  const int g = blockIdx.x * 256 + threadIdx.x;   // 80 blocks
  if (g < 12288) {
    const int e = g * 8;
    const int imgblk = e >> 12, r = e & 4095;
    const int kc = r >> 10, row = (r & 1023) >> 3;
    const int mblk = imgblk / 12, kt32 = imgblk % 12;
    const float* s = W1 + (size_t)(mblk * 128 + row) * 384 + kt32 * 32 + kc * 8;
    const float4 f0 = *(const float4*)(s), f1 = *(const float4*)(s + 4);
    bf16x8_t h;
    h[0] = (bf16)f0.x; h[1] = (bf16)f0.y; h[2] = (bf16)f0.z; h[3] = (bf16)f0.w;
    h[4] = (bf16)f1.x; h[5] = (bf16)f1.y; h[6] = (bf16)f1.z; h[7] = (bf16)f1.w;
    *(bf16x8_t*)(img + e) = h;
  } else if (g < 20480) {
    const int e = (g - 12288) * 8;
    const int imgblk = e >> 12, r = e & 4095;
    const int kc = r >> 10, row = (r & 1023) >> 3;
    const int mblk = imgblk >> 3, kt32 = imgblk & 7;
    const float* s = W2 + (size_t)(mblk * 128 + row) * 256 + kt32 * 32 + kc * 8;
    const float4 f0 = *(const float4*)(s), f1 = *(const float4*)(s + 4);
    bf16x8_t h;
    h[0] = (bf16)f0.x; h[1] = (bf16)f0.y; h[2] = (bf16)f0.z; h[3] = (bf16)f0.w;
    h[4] = (bf16)f1.x; h[5] = (bf16)f1.y; h[6] = (bf16)f1.z; h[7] = (bf16)f1.w;
    *(bf16x8_t*)(img + 98304 + e) = h;
  }
}

// ---------------- kernel 5: GEMM1 via global_load_lds, XCD-swizzled, FUSED BN-STATS ---------
template<int K>
__global__ __launch_bounds__(256) void k_gemm(const bf16* __restrict__ Wimg, const float* __restrict__ bias,
                                              const bf16* __restrict__ X, bf16* __restrict__ Zp,
                                              float* __restrict__ part) {
  __shared__ bf16 As[4096];   // [kc(4)][row m(128)][kk(8)]
  __shared__ bf16 Bt[4096];
  __shared__ float stl[2][128][2];
  const int tid = threadIdx.x;
  const int lane = tid & 63, wid = tid >> 6;
  const int wr = wid >> 1, wc = wid & 1;
  const int dd = blockIdx.x;
  const int xcd = dd & 7, pos = dd >> 3;
  const int b = pos >> 4, q = pos & 15;
  const int m0 = (q & 1) * 128;
  const int ncol = xcd * 8 + (q >> 1);
  const int n0 = ncol * 128;
  const int mblk = m0 >> 7;
  const int l15 = lane & 15, l4 = lane >> 4;

  f32x4_t acc[4][4];
  #pragma unroll
  for (int i = 0; i < 4; ++i)
    #pragma unroll
    for (int j = 0; j < 4; ++j) { f32x4_t z = {0.f, 0.f, 0.f, 0.f}; acc[i][j] = z; }

  const bf16* Xb = X + (size_t)b * (K / 8) * ((size_t)N_ * 8);

  for (int kt = 0; kt < K; kt += 32) {
    const bf16* asrc = Wimg + (size_t)(mblk * (K / 32) + (kt >> 5)) * 4096 + wid * 1024 + lane * 8;
    GL16(asrc,       &As[wid * 1024]);
    GL16(asrc + 512, &As[wid * 1024 + 512]);
    const bf16* bsrc = Xb + ((size_t)(kt >> 3) + wid) * ((size_t)N_ * 8) + ((size_t)n0 + lane) * 8;
    GL16(bsrc,       &Bt[wid * 1024]);
    GL16(bsrc + 512, &Bt[wid * 1024 + 512]);
    __syncthreads();
    bf16x8_t af[4], bfr[4];
    #pragma unroll
    for (int mi = 0; mi < 4; ++mi) af[mi]  = *(const bf16x8_t*)&As[l4 * 1024 + (wr * 64 + mi * 16 + l15) * 8];
    #pragma unroll
    for (int ni = 0; ni < 4; ++ni) bfr[ni] = *(const bf16x8_t*)&Bt[l4 * 1024 + (wc * 64 + ni * 16 + l15) * 8];
    #pragma unroll
    for (int mi = 0; mi < 4; ++mi)
      #pragma unroll
      for (int ni = 0; ni < 4; ++ni)
        acc[mi][ni] = __builtin_amdgcn_mfma_f32_16x16x32_bf16(af[mi], bfr[ni], acc[mi][ni], 0, 0, 0);
    __syncthreads();
  }
  bf16* Zb = Zp + (size_t)b * 32 * ((size_t)N_ * 8);
  #pragma unroll
  for (int mi = 0; mi < 4; ++mi) {
    const int obase = m0 + wr * 64 + mi * 16 + l4 * 4;
    const float4 bv = *(const float4*)(bias + obase);
    const size_t gofs = (size_t)(obase >> 3) * ((size_t)N_ * 8) + (obase & 7);
    float sv0 = 0.f, sv1 = 0.f, sv2 = 0.f, sv3 = 0.f;
    float qv0 = 0.f, qv1 = 0.f, qv2 = 0.f, qv3 = 0.f;
    #pragma unroll
    for (int ni = 0; ni < 4; ++ni) {
      const int nn = n0 + wc * 64 + ni * 16 + l15;
      const float v0 = acc[mi][ni][0] + bv.x;
      const float v1 = acc[mi][ni][1] + bv.y;
      const float v2 = acc[mi][ni][2] + bv.z;
      const float v3 = acc[mi][ni][3] + bv.w;
      bf16x4_t o;
      o[0] = (bf16)v0; o[1] = (bf16)v1; o[2] = (bf16)v2; o[3] = (bf16)v3;
      *(bf16x4_t*)(Zb + gofs + (size_t)nn * 8) = o;
      sv0 += v0; qv0 = fmaf(v0, v0, qv0);
      sv1 += v1; qv1 = fmaf(v1, v1, qv1);
      sv2 += v2; qv2 = fmaf(v2, v2, qv2);
      sv3 += v3; qv3 = fmaf(v3, v3, qv3);
    }
    #pragma unroll
    for (int off = 1; off < 16; off <<= 1) {
      sv0 += __shfl_xor(sv0, off); qv0 += __shfl_xor(qv0, off);
      sv1 += __shfl_xor(sv1, off); qv1 += __shfl_xor(qv1, off);
      sv2 += __shfl_xor(sv2, off); qv2 += __shfl_xor(qv2, off);
      sv3 += __shfl_xor(sv3, off); qv3 += __shfl_xor(qv3, off);
    }
    if (l15 == 0) {
      const int ol = wr * 64 + mi * 16 + l4 * 4;
      stl[wc][ol + 0][0] = sv0; stl[wc][ol + 0][1] = qv0;
      stl[wc][ol + 1][0] = sv1; stl[wc][ol + 1][1] = qv1;
      stl[wc][ol + 2][0] = sv2; stl[wc][ol + 2][1] = qv2;
      stl[wc][ol + 3][0] = sv3; stl[wc][ol + 3][1] = qv3;
    }
  }
  __syncthreads();
  if (tid < 128) {
    const float s  = stl[0][tid][0] + stl[1][tid][0];
    const float sq = stl[0][tid][1] + stl[1][tid][1];
    const int ib = b * 64 + ncol;
    part[(size_t)(m0 + tid) * 512 + ib]       = s;
    part[(size_t)(256 + m0 + tid) * 512 + ib] = sq;
  }
}

// ---------------- kernel 5b: GEMM2 with FUSED BN1+ReLU on B-staging ----------
__global__ __launch_bounds__(256) void k_gemm2f(const bf16* __restrict__ Wimg, const float* __restrict__ bias,
                                                const bf16* __restrict__ Z1, const float* __restrict__ ss,
                                                bf16* __restrict__ Zp, float* __restrict__ part) {
  __shared__ bf16 As[4096];
  __shared__ bf16 Bt[4096];
  __shared__ float stl[2][128][2];
  __shared__ float ssl[512];
  const int tid = threadIdx.x;
  const int lane = tid & 63, wid = tid >> 6;
  const int wr = wid >> 1, wc = wid & 1;
  const int dd = blockIdx.x;
  const int xcd = dd & 7, pos = dd >> 3;
  const int b = pos >> 4, q = pos & 15;
  const int m0 = (q & 1) * 128;
  const int ncol = xcd * 8 + (q >> 1);
  const int n0 = ncol * 128;
  const int mblk = m0 >> 7;
  const int l15 = lane & 15, l4 = lane >> 4;

  ssl[tid] = ss[tid]; ssl[256 + tid] = ss[256 + tid];

  f32x4_t acc[4][4];
  #pragma unroll
  for (int i = 0; i < 4; ++i)
    #pragma unroll
    for (int j = 0; j < 4; ++j) { f32x4_t z = {0.f, 0.f, 0.f, 0.f}; acc[i][j] = z; }

  const bf16* Z1b = Z1 + (size_t)b * 32 * ((size_t)N_ * 8);
  __syncthreads();   // ssl ready

  for (int kt = 0; kt < 256; kt += 32) {
    const bf16* asrc = Wimg + (size_t)(mblk * 8 + (kt >> 5)) * 4096 + wid * 1024 + lane * 8;
    GL16(asrc,       &As[wid * 1024]);
    GL16(asrc + 512, &As[wid * 1024 + 512]);
    const int kc8 = (kt >> 3) + wid;
    const bf16* bsrc = Z1b + (size_t)kc8 * ((size_t)N_ * 8) + ((size_t)n0 + lane) * 8;
    const bf16x8_t rb0 = *(const bf16x8_t*)(bsrc);
    const bf16x8_t rb1 = *(const bf16x8_t*)(bsrc + 512);
    const int cb = kc8 * 8;
    bf16x8_t ob0, ob1;
    #pragma unroll
    for (int j = 0; j < 8; ++j) {
      const float sc = ssl[cb + j], sh = ssl[256 + cb + j];
      ob0[j] = (bf16)fmaxf(fmaf((float)rb0[j], sc, sh), 0.f);
      ob1[j] = (bf16)fmaxf(fmaf((float)rb1[j], sc, sh), 0.f);
    }
    *(bf16x8_t*)&Bt[wid * 1024 + lane * 8]       = ob0;
    *(bf16x8_t*)&Bt[wid * 1024 + 512 + lane * 8] = ob1;
    __syncthreads();
    bf16x8_t af[4], bfr[4];
    #pragma unroll
    for (int mi = 0; mi < 4; ++mi) af[mi]  = *(const bf16x8_t*)&As[l4 * 1024 + (wr * 64 + mi * 16 + l15) * 8];
    #pragma unroll
    for (int ni = 0; ni < 4; ++ni) bfr[ni] = *(const bf16x8_t*)&Bt[l4 * 1024 + (wc * 64 + ni * 16 + l15) * 8];
    #pragma unroll
    for (int mi = 0; mi < 4; ++mi)
      #pragma unroll
      for (int ni = 0; ni < 4; ++ni)
        acc[mi][ni] = __builtin_amdgcn_mfma_f32_16x16x32_bf16(af[mi], bfr[ni], acc[mi][ni], 0, 0, 0);
    __syncthreads();
  }
  bf16* Zb = Zp + (size_t)b * 32 * ((size_t)N_ * 8);
  #pragma unroll
  for (int mi = 0; mi < 4; ++mi) {
    const int obase = m0 + wr * 64 + mi * 16 + l4 * 4;
    const float4 bv = *(const float4*)(bias + obase);
    const size_t gofs = (size_t)(obase >> 3) * ((size_t)N_ * 8) + (obase & 7);
    float sv0 = 0.f, sv1 = 0.f, sv2 = 0.f, sv3 = 0.f;
    float qv0 = 0.f, qv1 = 0.f, qv2 = 0.f, qv3 = 0.f;
    #pragma unroll
    for (int ni = 0; ni < 4; ++ni) {
      const int nn = n0 + wc * 64 + ni * 16 + l15;
      const float v0 = acc[mi][ni][0] + bv.x;
      const float v1 = acc[mi][ni][1] + bv.y;
      const float v2 = acc[mi][ni][2] + bv.z;
      const float v3 = acc[mi][ni][3] + bv.w;
      bf16x4_t o;
      o[0] = (bf16)v0; o[1] = (bf16)v1; o[2] = (bf16)v2; o[3] = (bf16)v3;
      *(bf16x4_t*)(Zb + gofs + (size_t)nn * 8) = o;
      sv0 += v0; qv0 = fmaf(v0, v0, qv0);
      sv1 += v1; qv1 = fmaf(v1, v1, qv1);
      sv2 += v2; qv2 = fmaf(v2, v2, qv2);
      sv3 += v3; qv3 = fmaf(v3, v3, qv3);
    }
    #pragma unroll
    for (int off = 1; off < 16; off <<= 1) {
      sv0 += __shfl_xor(sv0, off); qv0 += __shfl_xor(qv0, off);
      sv1 += __shfl_xor(sv1, off); qv1 += __shfl_xor(qv1, off);
      sv2 += __shfl_xor(sv2, off); qv2 += __shfl_xor(qv2, off);
      sv3 += __shfl_xor(sv3, off); qv3 += __shfl_xor(qv3, off);
    }
    if (l15 == 0) {
      const int ol = wr * 64 + mi * 16 + l4 * 4;
      stl[wc][ol + 0][0] = sv0; stl[wc][ol + 0][1] = qv0;
      stl[wc][ol + 1][0] = sv1; stl[wc][ol + 1][1] = qv1;
      stl[wc][ol + 2][0] = sv2; stl[wc][ol + 2][1] = qv2;
      stl[wc][ol + 3][0] = sv3; stl[wc][ol + 3][1] = qv3;
    }
  }
  __syncthreads();
  if (tid < 128) {
    const float s  = stl[0][tid][0] + stl[1][tid][0];
    const float sq = stl[0][tid][1] + stl[1][tid][1];
    const int ib = b * 64 + ncol;
    part[(size_t)(m0 + tid) * 512 + ib]       = s;
    part[(size_t)(256 + m0 + tid) * 512 + ib] = sq;
  }
}

// ---------------- kernel 6: finalize scale/shift from partials (256 blocks) ----------------
__global__ __launch_bounds__(256) void k_ss(const float* __restrict__ part, const float* __restrict__ g,
                                            const float* __restrict__ be, float* __restrict__ ss) {
  const int c = blockIdx.x, t = threadIdx.x;
  float s  = part[(size_t)c * 512 + t]         + part[(size_t)c * 512 + t + 256];
  float qv = part[(size_t)(256 + c) * 512 + t] + part[(size_t)(256 + c) * 512 + t + 256];
  #pragma unroll
  for (int off = 32; off; off >>= 1) { s += __shfl_down(s, off); qv += __shfl_down(qv, off); }
  __shared__ float r[8];
  const int w = t >> 6;
  if ((t & 63) == 0) { r[w] = s; r[4 + w] = qv; }
  __syncthreads();
  if (t == 0) {
    s  = r[0] + r[1] + r[2] + r[3];
    qv = r[4] + r[5] + r[6] + r[7];
    const float mean = s * (1.f / 65536.f);
    const float var  = qv * (1.f / 65536.f) - mean * mean;
    const float rstd = rsqrtf(var + 1e-5f);
    const float sc = g[c] * rstd;
    ss[c] = sc; ss[O_ + c] = be[c] - mean * sc;
  }
}

// ---------------- kernel 7: final BN+ReLU, panels -> Y fp32 [B][256][N] ----------------
__global__ __launch_bounds__(256) void k_final_p(const bf16* __restrict__ Z, const float* __restrict__ ss,
                                                 float* __restrict__ Y) {
  const int b  = blockIdx.x >> 7;
  const int n0 = (blockIdx.x & 127) * 64;
  const int og = threadIdx.x >> 3, ns = threadIdx.x & 7;
  const bf16* src = Z + (((size_t)b * 32 + og) * N_ + n0 + ns * 8) * 8;
  bf16x8_t v[8];
  #pragma unroll
  for (int i = 0; i < 8; ++i) v[i] = *(const bf16x8_t*)(src + i * 8);
  float sc[8], sh[8];
  #pragma unroll
  for (int j = 0; j < 8; ++j) { sc[j] = ss[og * 8 + j]; sh[j] = ss[O_ + og * 8 + j]; }
  float* dst = Y + ((size_t)b * O_ + og * 8) * N_ + n0 + ns * 8;
  #pragma unroll
  for (int j = 0; j < 8; ++j) {
    float4 a0, a1;
    a0.x = fmaxf(fmaf((float)v[0][j], sc[j], sh[j]), 0.f);
    a0.y = fmaxf(fmaf((float)v[1][j], sc[j], sh[j]), 0.f);
    a0.z = fmaxf(fmaf((float)v[2][j], sc[j], sh[j]), 0.f);
    a0.w = fmaxf(fmaf((float)v[3][j], sc[j], sh[j]), 0.f);
    a1.x = fmaxf(fmaf((float)v[4][j], sc[j], sh[j]), 0.f);
    a1.y = fmaxf(fmaf((float)v[5][j], sc[j], sh[j]), 0.f);
    a1.z = fmaxf(fmaf((float)v[6][j], sc[j], sh[j]), 0.f);
    a1.w = fmaxf(fmaf((float)v[7][j], sc[j], sh[j]), 0.f);
    *(float4*)(dst + (size_t)j * N_)     = a0;
    *(float4*)(dst + (size_t)j * N_ + 4) = a1;
  }
}

extern "C" void kernel_launch(void* const* d_in, const int* in_sizes, int n_in,
                              void* d_out, int out_size, void* d_ws, size_t ws_size,
                              hipStream_t stream) {
  const float* xyz1    = (const float*)d_in[0];
  const float* xyz2    = (const float*)d_in[1];
  const float* points1 = (const float*)d_in[2];
  const float* points2 = (const float*)d_in[3];
  const float* W1  = (const float*)d_in[4];
  const float* b1  = (const float*)d_in[5];
  const float* g1  = (const float*)d_in[6];
  const float* be1 = (const float*)d_in[7];
  const float* W2  = (const float*)d_in[8];
  const float* b2  = (const float*)d_in[9];
  const float* g2  = (const float*)d_in[10];
  const float* be2 = (const float*)d_in[11];
  float* Y = (float*)d_out;
  char*  ws = (char*)d_ws;
  int*   idxw  = (int*)(ws + OFF_IDX);
  float* www   = (float*)(ws + OFF_W);
  bf16*  wimg1 = (bf16*)(ws + OFF_IDX);   // reuses idx region AFTER k_interp
  bf16*  wimg2 = wimg1 + 98304;
  float* part  = (float*)(ws + OFF_PRT);  // reuses idx/www tail AFTER k_interp
  bf16*  xp    = (bf16*)(ws + OFF_XP);
  bf16*  z1    = (bf16*)(ws + OFF_Z);     // also f2t (disjoint lifetime)
  bf16*  f2t   = (bf16*)(ws + OFF_Z);
  bf16*  z2    = (bf16*)(ws + OFF_XP);    // aliases xp (dead after gemm1)
  float* ss1   = (float*)(ws + OFF_SS1);
  float* ss2   = (float*)(ws + OFF_SS2);

  hipLaunchKernelGGL(k_prep, dim3(2048), dim3(256), 0, stream, points1, xp, points2, f2t);
  hipLaunchKernelGGL(k_nn3, dim3(128, 8), dim3(256), 0, stream, xyz1, xyz2, idxw, www);
  hipLaunchKernelGGL(k_interp, dim3(8192), dim3(256), 0, stream, f2t, idxw, www, xp);
  hipLaunchKernelGGL(k_wprep, dim3(80), dim3(256), 0, stream, W1, W2, wimg1);
  hipLaunchKernelGGL((k_gemm<384>), dim3(1024), dim3(256), 0, stream, wimg1, b1, xp, z1, part);
  hipLaunchKernelGGL(k_ss, dim3(256), dim3(256), 0, stream, part, g1, be1, ss1);
  hipLaunchKernelGGL(k_gemm2f, dim3(1024), dim3(256), 0, stream, wimg2, b2, z1, ss1, z2, part);
  hipLaunchKernelGGL(k_ss, dim3(256), dim3(256), 0, stream, part, g2, be2, ss2);
  hipLaunchKernelGGL(k_final_p, dim3(1024), dim3(256), 0, stream, z2, ss2, Y);
}